// Round 16
// baseline (40.144 us; speedup 1.0000x reference)
//
#include <hip/hip_runtime.h>
#include <hip/hip_bf16.h>

#define OUT_N 8192
#define IN_N  8192
#define QROW  (IN_N / 2)     // 4096 int32 per out row (one widened byte each)
#define NSC   16             // superchunks: 1 KB of q-stream per row each
#define SC32  256            // int32 per row per superchunk

typedef __attribute__((ext_vector_type(8))) short short8v;  // 8 bf16
typedef __attribute__((ext_vector_type(4))) float f32x4;

__device__ __forceinline__ unsigned int bf16pk(float a, float b) {
    __hip_bfloat162 h = __float22bfloat162_rn(make_float2(a, b));
    unsigned int u;
    __builtin_memcpy(&u, &h, 4);
    return u;
}

// async global->LDS, 16B/lane; LDS dest = wave-uniform base + lane*16 (HW rule)
__device__ __forceinline__ void gld_lds16(const int* gsrc, int* ldst_base) {
    __builtin_amdgcn_global_load_lds(
        (const __attribute__((address_space(1))) void*)gsrc,
        (__attribute__((address_space(3))) void*)ldst_base, 16, 0, 0);
}

#define SCHED0() __builtin_amdgcn_sched_barrier(0)
#define CFENCE() asm volatile("" ::: "memory")

// Pre-pass: x fp32 -> bf16, permuted to consumer consume-order:
// flat uint4 slot cw*4096 + S*256 + s*64 + l = bf16x8 of
// x[row=l&15][S*512 + cw*128 + s*32 + (l>>4)*8 ..+8] -> main-kernel x loads
// are wave-uniform base + l*16B (fully contiguous 1 KB per instr).
__global__ __launch_bounds__(256) void xconv_kernel(
    const float* __restrict__ x, uint4* __restrict__ xb2)
{
    const int tid = blockIdx.x * 256 + threadIdx.x;   // 16384 uint4 outputs
    const int l  = tid & 63;
    const int s  = (tid >> 6) & 3;
    const int S  = (tid >> 8) & 15;
    const int cw = tid >> 12;
    const int r  = l & 15;
    const int g  = l >> 4;
    const float* src = x + (size_t)r * IN_N + S * 512 + cw * 128 + s * 32 + g * 8;
    float4 a = *(const float4*)src;
    float4 b = *(const float4*)(src + 4);
    uint4 u = { bf16pk(a.x, a.y), bf16pk(a.z, a.w),
                bf16pk(b.x, b.y), bf16pk(b.z, b.w) };
    xb2[tid] = u;
}

// Producer/consumer wave specialization. One block = one 16-out-row tile.
// Waves 0-3 (producers): DMA q in 1-KB-CONTIGUOUS single-row instructions
// (producer p owns rows 4p..4p+3; superchunk S = 16 rows x 1 KB, dbuf by S&1).
// Waves 4-7 (consumers): consumer cw computes k-quarter of each superchunk
// (4 MFMA steps x 16 superchunks = 64 steps).
// Sync: LDS flags, NO s_barrier in the loop. Producer: vmcnt(4) own-DMA wait
// -> psync[S][p]=1; issues S+2 only after pdone[S] (slot reuse safe).
// Consumer: spin psync[S] -> compute -> lgkmcnt(0) -> pdone[S][cw]=1.
// q LDS swizzle: logical slot j of row r at physical j^(r&15), pre-applied on
// the per-lane DMA source (LDS dest linear, m173); 2-way on read = free.
__global__ __launch_bounds__(512, 4) void qlin_pc_kernel(
    const int*   __restrict__ qp,
    const uint4* __restrict__ xb2,
    const float* __restrict__ scale,
    const float* __restrict__ bias,
    float*       __restrict__ out)
{
    __shared__ int   qbuf[2][16][SC32];   // 2 x 16 KB = 32 KB
    __shared__ float red[4][16][17];      // 4.4 KB reduction scratch
    __shared__ int   psync[NSC][4];       // producer->consumer flags
    __shared__ int   pdone[NSC][4];       // consumer->producer flags

    const int t = threadIdx.x;
    const int w = t >> 6;
    const int l = t & 63;
    const int g = l >> 4;
    const int r = l & 15;
    const int tile = blockIdx.x;
    const int obase = tile * 16;

    if (t < NSC * 4) { ((int*)psync)[t] = 0; ((int*)pdone)[t] = 0; }
    __syncthreads();

    if (w < 4) {
        // ---------------- PRODUCER p: rows 4p..4p+3 ----------------
        const int p = w;
        // DMA(S): 4 instrs, each 1 KB contiguous of one row, source slot
        // XOR-permuted so physical LDS slot λ holds logical slot λ^(R&15)
#define PDMA(S_) do { _Pragma("unroll")                                      \
        for (int i = 0; i < 4; ++i) {                                        \
            const int R = 4 * p + i;                                         \
            gld_lds16(qp + (size_t)(obase + R) * QROW + (S_) * SC32          \
                         + ((l ^ (R & 15)) << 2),                            \
                      &qbuf[(S_) & 1][R][0]);                                \
        } } while (0)

        PDMA(0);
        PDMA(1);
        #pragma unroll
        for (int S = 0; S < NSC; ++S) {
            if (S + 1 < NSC) asm volatile("s_waitcnt vmcnt(4)" ::: "memory");
            else             asm volatile("s_waitcnt vmcnt(0)" ::: "memory");
            SCHED0();
            if (l == 0) psync[S][p] = 1;          // superchunk S resident
            if (S + 2 < NSC) {
                volatile int* dn = &pdone[S][0];  // consumers done with slot S&1
                while ((dn[0] & dn[1] & dn[2] & dn[3]) == 0)
                    asm volatile("s_sleep 1");
                CFENCE(); SCHED0();
                PDMA(S + 2);
            }
        }
#undef PDMA
    } else {
        // ---------------- CONSUMER cw: k-quarter ----------------
        const int cw = w - 4;
        f32x4 acc = {0.f, 0.f, 0.f, 0.f};
        const uint4* xbase = xb2 + cw * 4096 + l;   // + S*256 + s*64

        #pragma unroll
        for (int S = 0; S < NSC; ++S) {
            // issue x first: latency hides under the psync spin
            uint4 xr0 = xbase[S * 256 +   0];
            uint4 xr1 = xbase[S * 256 +  64];
            uint4 xr2 = xbase[S * 256 + 128];
            uint4 xr3 = xbase[S * 256 + 192];
            volatile int* sy = &psync[S][0];
            while ((sy[0] & sy[1] & sy[2] & sy[3]) == 0)
                asm volatile("s_sleep 1");
            CFENCE(); SCHED0();
            asm volatile("s_waitcnt vmcnt(0)" ::: "memory");   // x resident
            SCHED0();

            const char* wb = (const char*)&qbuf[S & 1][0][0];
            #pragma unroll
            for (int s = 0; s < 4; ++s) {
                const int slot = cw * 16 + s * 4 + g;          // logical
                const int4 q = *(const int4*)(wb + r * 1024
                                              + ((slot ^ (r & 15)) << 4));
                // nibble e=2m lo / e=2m+1 hi of byte m; signed; exact in bf16
                uint4 ub = {
                    bf16pk((float)((q.x << 28) >> 28), (float)((q.x << 24) >> 28)),
                    bf16pk((float)((q.y << 28) >> 28), (float)((q.y << 24) >> 28)),
                    bf16pk((float)((q.z << 28) >> 28), (float)((q.z << 24) >> 28)),
                    bf16pk((float)((q.w << 28) >> 28), (float)((q.w << 24) >> 28))
                };
                short8v bfrag = __builtin_bit_cast(short8v, ub);
                uint4 xcur = (s == 0) ? xr0 : (s == 1) ? xr1 : (s == 2) ? xr2 : xr3;
                short8v afrag = __builtin_bit_cast(short8v, xcur);
                acc = __builtin_amdgcn_mfma_f32_16x16x32_bf16(afrag, bfrag, acc, 0, 0, 0);
            }
            asm volatile("s_waitcnt lgkmcnt(0)" ::: "memory"); // reads retired
            SCHED0();
            if (l == 0) pdone[S][cw] = 1;
        }

        // D map: col=lane&15 (out), row=(lane>>4)*4+j (batch)
        red[cw][g * 4 + 0][r] = acc[0];
        red[cw][g * 4 + 1][r] = acc[1];
        red[cw][g * 4 + 2][r] = acc[2];
        red[cw][g * 4 + 3][r] = acc[3];
    }

    __syncthreads();

    if (t < 256) {
        const int b = t >> 4;            // batch
        const int o = t & 15;            // out within tile
        const int oc = obase + o;
        float v = red[0][b][o] + red[1][b][o] + red[2][b][o] + red[3][b][o];
        out[b * OUT_N + oc] = v * scale[oc >> 7] + bias[oc];
    }
}

extern "C" void kernel_launch(void* const* d_in, const int* in_sizes, int n_in,
                              void* d_out, int out_size, void* d_ws, size_t ws_size,
                              hipStream_t stream) {
    (void)in_sizes; (void)n_in; (void)ws_size; (void)out_size;
    const float* x     = (const float*)d_in[0];
    const int*   qp    = (const int*)d_in[1];
    const float* scale = (const float*)d_in[2];
    const float* bias  = (const float*)d_in[3];
    float*       out   = (float*)d_out;
    uint4*       xb2   = (uint4*)d_ws;     // 256 KB permuted bf16 x

    xconv_kernel<<<dim3(64), dim3(256), 0, stream>>>(x, xb2);
    qlin_pc_kernel<<<dim3(OUT_N / 16), dim3(512), 0, stream>>>(qp, xb2, scale, bias, out);
}